// Round 6
// baseline (848.998 us; speedup 1.0000x reference)
//
#include <hip/hip_runtime.h>
#include <math.h>

// Sparse2L round 6: T4 counted-vmcnt 3-deep pipeline in all GEMM K-loops
// (raw s_barrier + s_waitcnt vmcnt(N), never 0 in steady state), xupc retiled
// to 64x128, t=0 specialization, fused setup. 22 launches.
//  per step: R = x@W - inputs; z = u@V (mini-GEMM in XUPC);
//            x = softthr(x - 2lr*(R@W^T), lr*gamma*up((1+e^-z)/2));  [x bf16]
//            gin = (-e^-z/2) * maxpool2x2(x) * gamma  (fused pool phase);
//            u = softthr(u - lr*(gin@V^T), lr*gamma/10)   [in H kernel]
//  output = x9 @ W
// GEMM: A [M][K] bf16 row-major, B in B^T layout [N][K] bf16, MFMA 16x16x32.
// LDS tiles [rows][64] bf16, seg^(row&7) XOR swizzle on BOTH global_load_lds
// source and ds_read_b128 (verified: SQ_LDS_BANK_CONFLICT == 0).

#define NB 4096
#define IN_DIM 512
#define OUT_DIM 4096
#define CAUSES_DIM 256
#define POOLED_DIM 1024

typedef __attribute__((ext_vector_type(8))) short short8;
typedef __attribute__((ext_vector_type(4))) float f32x4;

static constexpr float LR = 0.001f;
static constexpr float GAMMA = 0.1f;

enum { EP_R = 0, EP_OUT, EP_UUP };

__device__ __forceinline__ float softthr(float v, float t) {
    return fmaxf(v - t, 0.0f) + fminf(v + t, 0.0f);
}
__device__ __forceinline__ unsigned short f2bf(float f) {
    unsigned int u = __builtin_bit_cast(unsigned int, f);
    u = (u + 0x7fffu + ((u >> 16) & 1u)) >> 16;
    return (unsigned short)u;
}
__device__ __forceinline__ float bf2f(unsigned short h) {
    return __builtin_bit_cast(float, (unsigned int)h << 16);
}
__device__ __forceinline__ void gload_lds16(const unsigned short* g, unsigned short* l) {
    __builtin_amdgcn_global_load_lds(
        (const __attribute__((address_space(1))) void*)g,
        (__attribute__((address_space(3))) void*)l, 16, 0, 0);
}

// stage ROWS x 64 bf16 tile; linear LDS dest, inverse-swizzled global source.
template<int ROWS, int K>
__device__ __forceinline__ void stage_tile(const unsigned short* __restrict__ g,
                                           unsigned short* l, int row0, int k0, int t)
{
#pragma unroll
    for (int j = 0; j < ROWS / 32; j++) {
        const int idx = j * 256 + t;
        const int row = idx >> 3;
        const int sl  = (idx & 7) ^ (row & 7);
        gload_lds16(g + (size_t)(row0 + row) * K + k0 + sl * 8,
                    l + (size_t)(idx & ~63) * 8);
    }
}

// ---------------------------------------------------------------------------
// Counted-vmcnt 3-buffer pipelined K-loop (T3+T4). Per stage each wave issues
// L = (BM+BN)/32 global_load_lds; steady state keeps 2 stages (2L) in flight.
// Tail peels with vmcnt(L) then vmcnt(0). Two raw s_barriers per K-step.
// ---------------------------------------------------------------------------
template<int BM, int BN, int K>
__device__ __forceinline__ void kloop(unsigned short* lds,
    const unsigned short* __restrict__ A, const unsigned short* __restrict__ B,
    int m0, int n0, f32x4 (&acc)[BM / 32][BN / 32])
{
    constexpr int FM = BM / 32, FN = BN / 32;
    constexpr int NK = K / 64, ST = (BM + BN) * 64, L = (BM + BN) / 32;
    static_assert(NK >= 3, "pipeline needs >=3 K-tiles");
    const int t = threadIdx.x;
    const int lane = t & 63, wid = t >> 6;
    const int l15 = lane & 15, l7 = lane & 7, g = lane >> 4;
    const int wm0 = (wid >> 1) * (BM / 2), wn0 = (wid & 1) * (BN / 2);

    auto stage = [&](int s, int b) {
        stage_tile<BM, K>(A, lds + b * ST, m0, s * 64, t);
        stage_tile<BN, K>(B, lds + b * ST + BM * 64, n0, s * 64, t);
    };
    auto comp = [&](int b) {
        const unsigned short* As = lds + b * ST;
        const unsigned short* Bs = lds + b * ST + BM * 64;
#pragma unroll
        for (int ks = 0; ks < 2; ks++) {
            const int so = (((ks * 4) + g) ^ l7) * 8;
            short8 af[FM], bfv[FN];
#pragma unroll
            for (int fi = 0; fi < FM; fi++)
                af[fi] = *(const short8*)&As[(wm0 + fi * 16 + l15) * 64 + so];
#pragma unroll
            for (int fj = 0; fj < FN; fj++)
                bfv[fj] = *(const short8*)&Bs[(wn0 + fj * 16 + l15) * 64 + so];
#pragma unroll
            for (int fi = 0; fi < FM; fi++)
#pragma unroll
                for (int fj = 0; fj < FN; fj++)
                    acc[fi][fj] = __builtin_amdgcn_mfma_f32_16x16x32_bf16(
                        af[fi], bfv[fj], acc[fi][fj], 0, 0, 0);
        }
    };

    stage(0, 0); stage(1, 1); stage(2, 2);
    int b = 0;
#pragma unroll 1
    for (int i = 0; i < NK - 2; ++i) {
        asm volatile("s_waitcnt vmcnt(%0)" :: "n"(2 * L) : "memory");
        __builtin_amdgcn_s_barrier();      // all waves: stage(i) landed
        comp(b);
        __builtin_amdgcn_s_barrier();      // all waves done reading buf b
        if (i + 3 < NK) stage(i + 3, b);
        b = (b == 2) ? 0 : b + 1;
    }
    asm volatile("s_waitcnt vmcnt(%0)" :: "n"(L) : "memory");
    __builtin_amdgcn_s_barrier();
    comp(b);
    b = (b == 2) ? 0 : b + 1;
    asm volatile("s_waitcnt vmcnt(0)" ::: "memory");
    __builtin_amdgcn_s_barrier();
    comp(b);
}

// ---------------------------------------------------------------------------
// generic GEMM core (EP_R / EP_OUT / EP_UUP)
// ---------------------------------------------------------------------------
template<int BM, int BN, int N, int K, int EP>
__device__ void gemm_core(unsigned short* lds, int bid,
                          const unsigned short* __restrict__ A,
                          const unsigned short* __restrict__ B,
                          const float* __restrict__ auxf,
                          void* __restrict__ out0, void* __restrict__ out1)
{
    constexpr int FM = BM / 32, FN = BN / 32;
    constexpr int NX = N / BN, NWG = (NB / BM) * NX;
    const int t = threadIdx.x, lane = t & 63, wid = t >> 6;
    const int l15 = lane & 15, g = lane >> 4;
    const int work = ((bid & 7) * (NWG / 8)) + (bid >> 3);
    const int bn = work % NX, bm = work / NX;
    const int m0 = bm * BM, n0 = bn * BN;
    const int wm0 = (wid >> 1) * (BM / 2), wn0 = (wid & 1) * (BN / 2);

    f32x4 acc[FM][FN];
#pragma unroll
    for (int fi = 0; fi < FM; fi++)
#pragma unroll
        for (int fj = 0; fj < FN; fj++) acc[fi][fj] = (f32x4){0.f, 0.f, 0.f, 0.f};

    kloop<BM, BN, K>(lds, A, B, m0, n0, acc);

#pragma unroll
    for (int fi = 0; fi < FM; fi++) {
#pragma unroll
        for (int fj = 0; fj < FN; fj++) {
#pragma unroll
            for (int r = 0; r < 4; r++) {
                const int row = m0 + wm0 + fi * 16 + g * 4 + r;
                const int col = n0 + wn0 + fj * 16 + l15;
                const float v = acc[fi][fj][r];
                if (EP == EP_R) {
                    ((unsigned short*)out0)[(size_t)row * N + col] =
                        f2bf(v - auxf[(size_t)row * N + col]);
                } else if (EP == EP_OUT) {
                    ((float*)out0)[(size_t)row * N + col] = v;
                } else { // EP_UUP
                    float* up = (float*)out0;
                    const size_t idx = (size_t)row * CAUSES_DIM + col;
                    const float uv = softthr(up[idx] - LR * v, LR * GAMMA * 0.1f);
                    up[idx] = uv;
                    ((unsigned short*)out1)[idx] = f2bf(uv);
                }
            }
        }
    }
}

// ---------------------------------------------------------------------------
// XUPC: x-update GEMM (R@W^T, 64x128) + causes mini-GEMM (u@V) + fused pool
// LDS: 3x12288 shorts pipeline buffers (72KB) + 2048-uint czdc (8KB) = 80KB.
// ---------------------------------------------------------------------------
template<bool FIRST, bool POOLF>
__global__ __launch_bounds__(256)
void xupc_kernel(const unsigned short* __restrict__ Rbf,
                 const unsigned short* __restrict__ Wbf,
                 const unsigned short* __restrict__ ubf,
                 const unsigned short* __restrict__ VTbf,
                 unsigned short* __restrict__ xbf,
                 unsigned short* __restrict__ gbf)
{
    constexpr int BM = 64, BN = 128;
    constexpr int NX = OUT_DIM / BN;        // 32
    constexpr int NWG = (NB / BM) * NX;     // 2048
    __shared__ unsigned short lds[3 * (BM + BN) * 64 + 4096];
    unsigned* czdc = (unsigned*)(lds + 3 * (BM + BN) * 64);  // [64][32] cz|dc
    unsigned short* xs = lds;                                 // pool tile 64x130

    const int t = threadIdx.x, lane = t & 63, wid = t >> 6;
    const int l15 = lane & 15, g = lane >> 4;
    const int work = ((blockIdx.x & 7) * (NWG / 8)) + (blockIdx.x >> 3);
    const int bn = work % NX, bm = work / NX;
    const int m0 = bm * BM, n0 = bn * BN;
    const int wm0 = (wid >> 1) * 32, wn0 = (wid & 1) * 64;

    f32x4 acc[2][4];
#pragma unroll
    for (int fi = 0; fi < 2; fi++)
#pragma unroll
        for (int fj = 0; fj < 4; fj++) acc[fi][fj] = (f32x4){0.f, 0.f, 0.f, 0.f};
    kloop<64, 128, IN_DIM>(lds, Rbf, Wbf, m0, n0, acc);
    __syncthreads();

    // causes mini-GEMM: z[64x32] = u[m0:,:] @ V^T-layout rows bn*32..
    f32x4 zacc[2][1];
    zacc[0][0] = (f32x4){0.f, 0.f, 0.f, 0.f};
    zacc[1][0] = (f32x4){0.f, 0.f, 0.f, 0.f};
    kloop<64, 32, CAUSES_DIM>(lds, ubf, VTbf, m0, bn * 32, zacc);

    {   // z epilogue -> czdc (cz low16 | dc high16), bf16-rounded
        const int zc = (wid & 1) * 16 + l15;
#pragma unroll
        for (int fi = 0; fi < 2; fi++) {
#pragma unroll
            for (int r = 0; r < 4; r++) {
                const int zr = (wid >> 1) * 32 + fi * 16 + g * 4 + r;
                const float e = expf(-zacc[fi][0][r]);
                czdc[zr * 32 + zc] =
                    (unsigned)f2bf(0.5f + 0.5f * e) | ((unsigned)f2bf(-0.5f * e) << 16);
            }
        }
    }
    __syncthreads();

    // x-update epilogue
#pragma unroll
    for (int fi = 0; fi < 2; fi++) {
#pragma unroll
        for (int fj = 0; fj < 4; fj++) {
#pragma unroll
            for (int r = 0; r < 4; r++) {
                const int rloc = wm0 + fi * 16 + g * 4 + r;
                const int cloc = wn0 + fj * 16 + l15;
                const int pl = (cloc & 63) >> 1;
                const float cz = bf2f((unsigned short)(czdc[rloc * 32 + pl] & 0xffffu));
                const size_t idx = (size_t)(m0 + rloc) * OUT_DIM + n0 + cloc;
                const float xold = FIRST ? 0.0f : bf2f(xbf[idx]);
                const float xv = softthr(xold - 2.0f * LR * acc[fi][fj][r],
                                         LR * GAMMA * cz);
                const unsigned short xq = f2bf(xv);
                xbf[idx] = xq;
                if (POOLF) xs[rloc * 130 + cloc] = xq;
            }
        }
    }

    // fused maxpool2x2 + gin
    if (POOLF) {
        __syncthreads();
        const int p = t & 31;             // local pooled col
        const int rbase = (t >> 5) * 8;   // 8 groups x 8 rows
#pragma unroll
        for (int i = 0; i < 8; i++) {
            const int prow = rbase + i;
            const unsigned short* xr = &xs[prow * 130 + 2 * p];
            const float mx = fmaxf(fmaxf(bf2f(xr[0]), bf2f(xr[1])),
                                   fmaxf(bf2f(xr[64]), bf2f(xr[65])));
            const float dcv = bf2f((unsigned short)(czdc[prow * 32 + p] >> 16));
            gbf[(size_t)(m0 + prow) * POOLED_DIM + bn * 32 + p] = f2bf(dcv * mx * GAMMA);
        }
    }
}

// ---------------------------------------------------------------------------
// H: horizontal fusion of UUP_t (256 blocks) and R_{t+1} (256 blocks)
// ---------------------------------------------------------------------------
__global__ __launch_bounds__(256)
void h_uup_r_kernel(const unsigned short* __restrict__ gbf,
                    const unsigned short* __restrict__ Vbf,
                    float* __restrict__ u, unsigned short* __restrict__ ubf,
                    const unsigned short* __restrict__ xbf,
                    const unsigned short* __restrict__ WTbf,
                    const float* __restrict__ inputs,
                    unsigned short* __restrict__ Rbf)
{
    __shared__ unsigned short lds[3 * (128 + 64) * 64];   // 72KB
    if (blockIdx.x < 256) {
        gemm_core<128, 64, IN_DIM, OUT_DIM, EP_R>(
            lds, blockIdx.x, xbf, WTbf, inputs, Rbf, nullptr);
    } else {
        gemm_core<64, 64, CAUSES_DIM, POOLED_DIM, EP_UUP>(
            lds, blockIdx.x - 256, gbf, Vbf, nullptr, u, ubf);
    }
}

__global__ __launch_bounds__(256)
void out_kernel(const unsigned short* __restrict__ xbf,
                const unsigned short* __restrict__ WTbf,
                float* __restrict__ out)
{
    __shared__ unsigned short lds[3 * (128 + 64) * 64];
    gemm_core<128, 64, IN_DIM, OUT_DIM, EP_OUT>(
        lds, blockIdx.x, xbf, WTbf, nullptr, out, nullptr);
}

// ---------------------------------------------------------------------------
// setup kernels
// ---------------------------------------------------------------------------
// cast + transpose in one pass: direct[r][c]=bf(in[r][c]); transp[c][r]=same
__global__ __launch_bounds__(256)
void prep_k(const float* __restrict__ in, unsigned short* __restrict__ direct,
            unsigned short* __restrict__ transp, int R, int C)
{
    __shared__ float tile[32][33];
    const int bx = blockIdx.x * 32, by = blockIdx.y * 32;
    const int tx = threadIdx.x % 32, ty = threadIdx.x / 32;
#pragma unroll
    for (int i = 0; i < 32; i += 8) {
        const float v = in[(size_t)(by + ty + i) * C + bx + tx];
        tile[ty + i][tx] = v;
        direct[(size_t)(by + ty + i) * C + bx + tx] = f2bf(v);
    }
    __syncthreads();
#pragma unroll
    for (int i = 0; i < 32; i += 8)
        transp[(size_t)(bx + ty + i) * R + by + tx] = f2bf(tile[tx][ty + i]);
}

__global__ void negcast_k(const float* __restrict__ in, unsigned short* __restrict__ out,
                          int n4)
{
    const int i = blockIdx.x * 256 + threadIdx.x;
    if (i >= n4) return;
    float4 v = ((const float4*)in)[i];
    union { unsigned short s[4]; unsigned long long u; } p;
    p.s[0] = f2bf(-v.x); p.s[1] = f2bf(-v.y); p.s[2] = f2bf(-v.z); p.s[3] = f2bf(-v.w);
    ((unsigned long long*)out)[i] = p.u;
}

__global__ void fill_u_k(float* __restrict__ u, unsigned short* __restrict__ ubf, int n) {
    const int i = blockIdx.x * 256 + threadIdx.x;
    if (i >= n) return;
    u[i] = 0.1f;
    ubf[i] = f2bf(0.1f);
}

extern "C" void kernel_launch(void* const* d_in, const int* in_sizes, int n_in,
                              void* d_out, int out_size, void* d_ws, size_t ws_size,
                              hipStream_t stream)
{
    const float* inputs = (const float*)d_in[0];   // [4096, 512]
    const float* W      = (const float*)d_in[1];   // [4096, 512]
    const float* V      = (const float*)d_in[2];   // [256, 1024]
    float* out = (float*)d_out;                    // [4096, 512]

    // workspace (~59 MB)
    char* w = (char*)d_ws;
    unsigned short* xbf  = (unsigned short*)w; w += (size_t)NB * OUT_DIM * 2;
    unsigned short* Rbf  = (unsigned short*)w; w += (size_t)NB * IN_DIM * 2;
    unsigned short* gbf  = (unsigned short*)w; w += (size_t)NB * POOLED_DIM * 2;
    float*          u    = (float*)w;          w += (size_t)NB * CAUSES_DIM * 4;
    unsigned short* ubf  = (unsigned short*)w; w += (size_t)NB * CAUSES_DIM * 2;
    unsigned short* Wbf  = (unsigned short*)w; w += (size_t)OUT_DIM * IN_DIM * 2;
    unsigned short* WTbf = (unsigned short*)w; w += (size_t)OUT_DIM * IN_DIM * 2;
    unsigned short* Vbf  = (unsigned short*)w; w += (size_t)CAUSES_DIM * POOLED_DIM * 2;
    unsigned short* VTbf = (unsigned short*)w;

    // ---- setup (4 launches) ----
    prep_k<<<dim3(IN_DIM / 32, OUT_DIM / 32), 256, 0, stream>>>(W, Wbf, WTbf, OUT_DIM, IN_DIM);
    prep_k<<<dim3(POOLED_DIM / 32, CAUSES_DIM / 32), 256, 0, stream>>>(V, Vbf, VTbf, CAUSES_DIM, POOLED_DIM);
    fill_u_k<<<NB * CAUSES_DIM / 256, 256, 0, stream>>>(u, ubf, NB * CAUSES_DIM);
    negcast_k<<<NB * IN_DIM / 4 / 256, 256, 0, stream>>>(inputs, Rbf, NB * IN_DIM / 4); // R0=-inputs

    // ---- 10-step scan ----
    xupc_kernel<true, true><<<2048, 256, 0, stream>>>(Rbf, Wbf, ubf, VTbf, xbf, gbf); // t=0, x=0
    h_uup_r_kernel<<<512, 256, 0, stream>>>(gbf, Vbf, u, ubf, xbf, WTbf, inputs, Rbf);
    for (int t = 1; t < 8; t++) {
        xupc_kernel<false, true><<<2048, 256, 0, stream>>>(Rbf, Wbf, ubf, VTbf, xbf, gbf);
        h_uup_r_kernel<<<512, 256, 0, stream>>>(gbf, Vbf, u, ubf, xbf, WTbf, inputs, Rbf);
    }
    xupc_kernel<false, false><<<2048, 256, 0, stream>>>(Rbf, Wbf, ubf, VTbf, xbf, gbf); // t=8
    out_kernel<<<256, 256, 0, stream>>>(xbf, WTbf, out);                                 // rec = x9@W
}

// Round 8
// 819.576 us; speedup vs baseline: 1.0359x; 1.0359x over previous
//
#include <hip/hip_runtime.h>
#include <math.h>

// Sparse2L round 7 (resubmit; r7 bench timed out): 128x128 xupc + 2-buffer
// counted-vmcnt kloop (T4) + L2-aware XCD work decode. 22 launches.
//  per step: R = x@W - inputs; z = u@V (mini-GEMM in XUPC);
//            x = softthr(x - 2lr*(R@W^T), lr*gamma*up((1+e^-z)/2));  [x bf16]
//            gin = (-e^-z/2) * maxpool2x2(x) * gamma  (fused pool phase);
//            u = softthr(u - lr*(gin@V^T), lr*gamma/10)   [in H kernel]
//  output = x9 @ W
// GEMM: A [M][K] bf16 row-major, B in B^T layout [N][K] bf16, MFMA 16x16x32.
// LDS tiles [rows][64] bf16, seg^(row&7) XOR swizzle on BOTH global_load_lds
// source and ds_read_b128.

#define NB 4096
#define IN_DIM 512
#define OUT_DIM 4096
#define CAUSES_DIM 256
#define POOLED_DIM 1024

typedef __attribute__((ext_vector_type(8))) short short8;
typedef __attribute__((ext_vector_type(4))) float f32x4;

static constexpr float LR = 0.001f;
static constexpr float GAMMA = 0.1f;

enum { EP_R = 0, EP_OUT, EP_UUP };

__device__ __forceinline__ float softthr(float v, float t) {
    return fmaxf(v - t, 0.0f) + fminf(v + t, 0.0f);
}
__device__ __forceinline__ unsigned short f2bf(float f) {
    unsigned int u = __builtin_bit_cast(unsigned int, f);
    u = (u + 0x7fffu + ((u >> 16) & 1u)) >> 16;
    return (unsigned short)u;
}
__device__ __forceinline__ float bf2f(unsigned short h) {
    return __builtin_bit_cast(float, (unsigned int)h << 16);
}
__device__ __forceinline__ void gload_lds16(const unsigned short* g, unsigned short* l) {
    __builtin_amdgcn_global_load_lds(
        (const __attribute__((address_space(1))) void*)g,
        (__attribute__((address_space(3))) void*)l, 16, 0, 0);
}

// stage ROWS x 64 bf16 tile; linear LDS dest, inverse-swizzled global source.
template<int ROWS, int K>
__device__ __forceinline__ void stage_tile(const unsigned short* __restrict__ g,
                                           unsigned short* l, int row0, int k0, int t)
{
#pragma unroll
    for (int j = 0; j < ROWS / 32; j++) {
        const int idx = j * 256 + t;
        const int row = idx >> 3;
        const int sl  = (idx & 7) ^ (row & 7);
        gload_lds16(g + (size_t)(row0 + row) * K + k0 + sl * 8,
                    l + (size_t)(idx & ~63) * 8);
    }
}

// ---------------------------------------------------------------------------
// 2-buffer counted-vmcnt pipelined K-loop (T4). Per stage each wave issues
// L=(BM+BN)/32 global_load_lds; steady-state waits vmcnt(L) (one tile still in
// flight during compute), drains to 0 only at the tail.
// ---------------------------------------------------------------------------
template<int BM, int BN, int K>
__device__ __forceinline__ void kloop2(unsigned short* lds,
    const unsigned short* __restrict__ A, const unsigned short* __restrict__ B,
    int m0, int n0, f32x4 (&acc)[BM / 32][BN / 32])
{
    constexpr int FM = BM / 32, FN = BN / 32;
    constexpr int NK = K / 64, ST = (BM + BN) * 64, L = (BM + BN) / 32;
    static_assert(NK >= 2, "pipeline needs >=2 K-tiles");
    const int t = threadIdx.x;
    const int lane = t & 63, wid = t >> 6;
    const int l15 = lane & 15, l7 = lane & 7, g = lane >> 4;
    const int wm0 = (wid >> 1) * (BM / 2), wn0 = (wid & 1) * (BN / 2);

    auto stage = [&](int s, int b) {
        stage_tile<BM, K>(A, lds + b * ST, m0, s * 64, t);
        stage_tile<BN, K>(B, lds + b * ST + BM * 64, n0, s * 64, t);
    };
    auto comp = [&](int b) {
        const unsigned short* As = lds + b * ST;
        const unsigned short* Bs = lds + b * ST + BM * 64;
#pragma unroll
        for (int ks = 0; ks < 2; ks++) {
            const int so = (((ks * 4) + g) ^ l7) * 8;
            short8 af[FM], bfv[FN];
#pragma unroll
            for (int fi = 0; fi < FM; fi++)
                af[fi] = *(const short8*)&As[(wm0 + fi * 16 + l15) * 64 + so];
#pragma unroll
            for (int fj = 0; fj < FN; fj++)
                bfv[fj] = *(const short8*)&Bs[(wn0 + fj * 16 + l15) * 64 + so];
#pragma unroll
            for (int fi = 0; fi < FM; fi++)
#pragma unroll
                for (int fj = 0; fj < FN; fj++)
                    acc[fi][fj] = __builtin_amdgcn_mfma_f32_16x16x32_bf16(
                        af[fi], bfv[fj], acc[fi][fj], 0, 0, 0);
        }
    };

    stage(0, 0); stage(1, 1);
    int b = 0;
#pragma unroll 1
    for (int i = 0; i < NK - 1; ++i) {
        asm volatile("s_waitcnt vmcnt(%0)" :: "n"(L) : "memory");
        __builtin_amdgcn_s_barrier();      // stage(i) landed for all waves
        comp(b);
        __builtin_amdgcn_s_barrier();      // all waves done reading buf b
        if (i + 2 < NK) stage(i + 2, b);
        b ^= 1;
    }
    asm volatile("s_waitcnt vmcnt(0)" ::: "memory");
    __builtin_amdgcn_s_barrier();
    comp(b);
}

// ---------------------------------------------------------------------------
// generic GEMM core (EP_R / EP_OUT / EP_UUP); caller provides m0,n0
// ---------------------------------------------------------------------------
template<int BM, int BN, int N, int K, int EP>
__device__ void gemm_core(unsigned short* lds, int m0, int n0,
                          const unsigned short* __restrict__ A,
                          const unsigned short* __restrict__ B,
                          const float* __restrict__ auxf,
                          void* __restrict__ out0, void* __restrict__ out1)
{
    constexpr int FM = BM / 32, FN = BN / 32;
    const int t = threadIdx.x, lane = t & 63, wid = t >> 6;
    const int l15 = lane & 15, g = lane >> 4;
    const int wm0 = (wid >> 1) * (BM / 2), wn0 = (wid & 1) * (BN / 2);

    f32x4 acc[FM][FN];
#pragma unroll
    for (int fi = 0; fi < FM; fi++)
#pragma unroll
        for (int fj = 0; fj < FN; fj++) acc[fi][fj] = (f32x4){0.f, 0.f, 0.f, 0.f};

    kloop2<BM, BN, K>(lds, A, B, m0, n0, acc);

#pragma unroll
    for (int fi = 0; fi < FM; fi++) {
#pragma unroll
        for (int fj = 0; fj < FN; fj++) {
#pragma unroll
            for (int r = 0; r < 4; r++) {
                const int row = m0 + wm0 + fi * 16 + g * 4 + r;
                const int col = n0 + wn0 + fj * 16 + l15;
                const float v = acc[fi][fj][r];
                if (EP == EP_R) {
                    ((unsigned short*)out0)[(size_t)row * N + col] =
                        f2bf(v - auxf[(size_t)row * N + col]);
                } else if (EP == EP_OUT) {
                    ((float*)out0)[(size_t)row * N + col] = v;
                } else { // EP_UUP
                    float* up = (float*)out0;
                    const size_t idx = (size_t)row * CAUSES_DIM + col;
                    const float uv = softthr(up[idx] - LR * v, LR * GAMMA * 0.1f);
                    up[idx] = uv;
                    ((unsigned short*)out1)[idx] = f2bf(uv);
                }
            }
        }
    }
}

// ---------------------------------------------------------------------------
// XUPC: x-update GEMM (R@W^T, 128x128) + causes mini-GEMM (u@V) + fused pool.
// LDS: 2x32KB pipeline buffers + 16KB czdc = 80KB -> 2 blocks/CU.
// Work decode: XCD owns 4 n-blocks x all 32 m; groups of 8m x 4n, n-fastest
// -> per-group L2 set = 1MB R-super + 0.5MB W panels (resident).
// ---------------------------------------------------------------------------
template<bool FIRST, bool POOLF>
__global__ __launch_bounds__(256)
void xupc_kernel(const unsigned short* __restrict__ Rbf,
                 const unsigned short* __restrict__ Wbf,
                 const unsigned short* __restrict__ ubf,
                 const unsigned short* __restrict__ VTbf,
                 unsigned short* __restrict__ xbf,
                 unsigned short* __restrict__ gbf)
{
    constexpr int BM = 128, BN = 128;
    __shared__ unsigned short lds[2 * (BM + BN) * 64 + 8192];  // 80 KB
    unsigned* czdc = (unsigned*)(lds + 2 * (BM + BN) * 64);    // [128][32] cz|dc
    unsigned short* xs = lds;                                  // pool tile 128x130

    const int t = threadIdx.x, lane = t & 63, wid = t >> 6;
    const int l15 = lane & 15, g = lane >> 4;
    // decode: xcd | supergroup g2 (8 m-blocks) | r: bm = g2*8 + r>>2, bn_local = r&3
    const int xcd = blockIdx.x & 7, l = blockIdx.x >> 3;       // l in [0,128)
    const int g2 = l >> 5, r2 = l & 31;
    const int bm = g2 * 8 + (r2 >> 2), bn = xcd * 4 + (r2 & 3);
    const int m0 = bm * BM, n0 = bn * BN;
    const int wm0 = (wid >> 1) * 64, wn0 = (wid & 1) * 64;

    f32x4 acc[4][4];
#pragma unroll
    for (int fi = 0; fi < 4; fi++)
#pragma unroll
        for (int fj = 0; fj < 4; fj++) acc[fi][fj] = (f32x4){0.f, 0.f, 0.f, 0.f};
    kloop2<128, 128, IN_DIM>(lds, Rbf, Wbf, m0, n0, acc);
    __syncthreads();

    // causes mini-GEMM: z[128x32] = u[m0:,:] @ VT rows [bn*32, bn*32+32)
    f32x4 zacc[4][1];
#pragma unroll
    for (int fi = 0; fi < 4; fi++) zacc[fi][0] = (f32x4){0.f, 0.f, 0.f, 0.f};
    kloop2<128, 32, CAUSES_DIM>(lds, ubf, VTbf, m0, bn * 32, zacc);

    {   // z epilogue -> czdc (cz low16 | dc high16), bf16-rounded
        const int zc = (wid & 1) * 16 + l15;
#pragma unroll
        for (int fi = 0; fi < 4; fi++) {
#pragma unroll
            for (int r = 0; r < 4; r++) {
                const int zr = (wid >> 1) * 64 + fi * 16 + g * 4 + r;
                const float e = expf(-zacc[fi][0][r]);
                czdc[zr * 32 + zc] =
                    (unsigned)f2bf(0.5f + 0.5f * e) | ((unsigned)f2bf(-0.5f * e) << 16);
            }
        }
    }
    __syncthreads();

    // x-update epilogue
#pragma unroll
    for (int fi = 0; fi < 4; fi++) {
#pragma unroll
        for (int fj = 0; fj < 4; fj++) {
#pragma unroll
            for (int r = 0; r < 4; r++) {
                const int rloc = wm0 + fi * 16 + g * 4 + r;
                const int cloc = wn0 + fj * 16 + l15;
                const int pl = (cloc & 63) >> 1;
                const float cz = bf2f((unsigned short)(czdc[rloc * 32 + pl] & 0xffffu));
                const size_t idx = (size_t)(m0 + rloc) * OUT_DIM + n0 + cloc;
                const float xold = FIRST ? 0.0f : bf2f(xbf[idx]);
                const float xv = softthr(xold - 2.0f * LR * acc[fi][fj][r],
                                         LR * GAMMA * cz);
                const unsigned short xq = f2bf(xv);
                xbf[idx] = xq;
                if (POOLF) xs[rloc * 130 + cloc] = xq;
            }
        }
    }

    // fused maxpool2x2 + gin
    if (POOLF) {
        __syncthreads();
        const int p = t & 31;              // local pooled col
        const int rbase = (t >> 5) * 16;   // 8 groups x 16 rows
#pragma unroll
        for (int i = 0; i < 16; i++) {
            const int prow = rbase + i;
            const unsigned short* xr = &xs[prow * 130 + 2 * p];
            const float mx = fmaxf(fmaxf(bf2f(xr[0]), bf2f(xr[1])),
                                   fmaxf(bf2f(xr[64]), bf2f(xr[65])));
            const float dcv = bf2f((unsigned short)(czdc[prow * 32 + p] >> 16));
            gbf[(size_t)(m0 + prow) * POOLED_DIM + bn * 32 + p] = f2bf(dcv * mx * GAMMA);
        }
    }
}

// ---------------------------------------------------------------------------
// H: horizontal fusion of UUP_t (256 blocks) and R_{t+1} (256 blocks).
// R decode: bn = bid&7 (one n-block per XCD -> WT panel 512KB L2-resident),
// bm = bid>>3.
// ---------------------------------------------------------------------------
__global__ __launch_bounds__(256)
void h_uup_r_kernel(const unsigned short* __restrict__ gbf,
                    const unsigned short* __restrict__ Vbf,
                    float* __restrict__ u, unsigned short* __restrict__ ubf,
                    const unsigned short* __restrict__ xbf,
                    const unsigned short* __restrict__ WTbf,
                    const float* __restrict__ inputs,
                    unsigned short* __restrict__ Rbf)
{
    __shared__ unsigned short lds[2 * (128 + 64) * 64];   // 48 KB
    if (blockIdx.x < 256) {
        const int bid = blockIdx.x;
        gemm_core<128, 64, IN_DIM, OUT_DIM, EP_R>(
            lds, (bid >> 3) * 128, (bid & 7) * 64, xbf, WTbf, inputs, Rbf, nullptr);
    } else {
        const int bid = blockIdx.x - 256;
        gemm_core<64, 64, CAUSES_DIM, POOLED_DIM, EP_UUP>(
            lds, (bid >> 2) * 64, (bid & 3) * 64, gbf, Vbf, nullptr, u, ubf);
    }
}

__global__ __launch_bounds__(256)
void out_kernel(const unsigned short* __restrict__ xbf,
                const unsigned short* __restrict__ WTbf,
                float* __restrict__ out)
{
    __shared__ unsigned short lds[2 * (128 + 64) * 64];
    const int bid = blockIdx.x;
    gemm_core<128, 64, IN_DIM, OUT_DIM, EP_OUT>(
        lds, (bid >> 3) * 128, (bid & 7) * 64, xbf, WTbf, nullptr, out, nullptr);
}

// ---------------------------------------------------------------------------
// setup kernels
// ---------------------------------------------------------------------------
// cast + transpose in one pass: direct[r][c]=bf(in[r][c]); transp[c][r]=same
__global__ __launch_bounds__(256)
void prep_k(const float* __restrict__ in, unsigned short* __restrict__ direct,
            unsigned short* __restrict__ transp, int R, int C)
{
    __shared__ float tile[32][33];
    const int bx = blockIdx.x * 32, by = blockIdx.y * 32;
    const int tx = threadIdx.x % 32, ty = threadIdx.x / 32;
#pragma unroll
    for (int i = 0; i < 32; i += 8) {
        const float v = in[(size_t)(by + ty + i) * C + bx + tx];
        tile[ty + i][tx] = v;
        direct[(size_t)(by + ty + i) * C + bx + tx] = f2bf(v);
    }
    __syncthreads();
#pragma unroll
    for (int i = 0; i < 32; i += 8)
        transp[(size_t)(bx + ty + i) * R + by + tx] = f2bf(tile[tx][ty + i]);
}

__global__ void negcast_k(const float* __restrict__ in, unsigned short* __restrict__ out,
                          int n4)
{
    const int i = blockIdx.x * 256 + threadIdx.x;
    if (i >= n4) return;
    float4 v = ((const float4*)in)[i];
    union { unsigned short s[4]; unsigned long long u; } p;
    p.s[0] = f2bf(-v.x); p.s[1] = f2bf(-v.y); p.s[2] = f2bf(-v.z); p.s[3] = f2bf(-v.w);
    ((unsigned long long*)out)[i] = p.u;
}

__global__ void fill_u_k(float* __restrict__ u, unsigned short* __restrict__ ubf, int n) {
    const int i = blockIdx.x * 256 + threadIdx.x;
    if (i >= n) return;
    u[i] = 0.1f;
    ubf[i] = f2bf(0.1f);
}

extern "C" void kernel_launch(void* const* d_in, const int* in_sizes, int n_in,
                              void* d_out, int out_size, void* d_ws, size_t ws_size,
                              hipStream_t stream)
{
    const float* inputs = (const float*)d_in[0];   // [4096, 512]
    const float* W      = (const float*)d_in[1];   // [4096, 512]
    const float* V      = (const float*)d_in[2];   // [256, 1024]
    float* out = (float*)d_out;                    // [4096, 512]

    // workspace (~59 MB)
    char* w = (char*)d_ws;
    unsigned short* xbf  = (unsigned short*)w; w += (size_t)NB * OUT_DIM * 2;
    unsigned short* Rbf  = (unsigned short*)w; w += (size_t)NB * IN_DIM * 2;
    unsigned short* gbf  = (unsigned short*)w; w += (size_t)NB * POOLED_DIM * 2;
    float*          u    = (float*)w;          w += (size_t)NB * CAUSES_DIM * 4;
    unsigned short* ubf  = (unsigned short*)w; w += (size_t)NB * CAUSES_DIM * 2;
    unsigned short* Wbf  = (unsigned short*)w; w += (size_t)OUT_DIM * IN_DIM * 2;
    unsigned short* WTbf = (unsigned short*)w; w += (size_t)OUT_DIM * IN_DIM * 2;
    unsigned short* Vbf  = (unsigned short*)w; w += (size_t)CAUSES_DIM * POOLED_DIM * 2;
    unsigned short* VTbf = (unsigned short*)w;

    // ---- setup (4 launches) ----
    prep_k<<<dim3(IN_DIM / 32, OUT_DIM / 32), 256, 0, stream>>>(W, Wbf, WTbf, OUT_DIM, IN_DIM);
    prep_k<<<dim3(POOLED_DIM / 32, CAUSES_DIM / 32), 256, 0, stream>>>(V, Vbf, VTbf, CAUSES_DIM, POOLED_DIM);
    fill_u_k<<<NB * CAUSES_DIM / 256, 256, 0, stream>>>(u, ubf, NB * CAUSES_DIM);
    negcast_k<<<NB * IN_DIM / 4 / 256, 256, 0, stream>>>(inputs, Rbf, NB * IN_DIM / 4); // R0=-inputs

    // ---- 10-step scan ----
    xupc_kernel<true, true><<<1024, 256, 0, stream>>>(Rbf, Wbf, ubf, VTbf, xbf, gbf); // t=0, x=0
    h_uup_r_kernel<<<512, 256, 0, stream>>>(gbf, Vbf, u, ubf, xbf, WTbf, inputs, Rbf);
    for (int t = 1; t < 8; t++) {
        xupc_kernel<false, true><<<1024, 256, 0, stream>>>(Rbf, Wbf, ubf, VTbf, xbf, gbf);
        h_uup_r_kernel<<<512, 256, 0, stream>>>(gbf, Vbf, u, ubf, xbf, WTbf, inputs, Rbf);
    }
    xupc_kernel<false, false><<<1024, 256, 0, stream>>>(Rbf, Wbf, ubf, VTbf, xbf, gbf); // t=8
    out_kernel<<<256, 256, 0, stream>>>(xbf, WTbf, out);                                 // rec = x9@W
}

// Round 9
// 737.133 us; speedup vs baseline: 1.1518x; 1.1118x over previous
//
#include <hip/hip_runtime.h>
#include <math.h>

// Sparse2L round 9: h/out R-part gets (a) XCD m-ownership decode (A-panels
// L2-resident per XCD, n-fastest reuse) and (b) 3-buffer counted-vmcnt kloop
// (steady-state vmcnt(2L), verified in r6). xupc unchanged from r7/r8.
//  per step: R = x@W - inputs; z = u@V (mini-GEMM in XUPC);
//            x = softthr(x - 2lr*(R@W^T), lr*gamma*up((1+e^-z)/2));  [x bf16]
//            gin = (-e^-z/2) * maxpool2x2(x) * gamma  (fused pool phase);
//            u = softthr(u - lr*(gin@V^T), lr*gamma/10)   [in H kernel]
//  output = x9 @ W
// GEMM: A [M][K] bf16 row-major, B in B^T layout [N][K] bf16, MFMA 16x16x32.
// LDS tiles [rows][64] bf16, seg^(row&7) XOR swizzle on BOTH global_load_lds
// source and ds_read_b128.

#define NB 4096
#define IN_DIM 512
#define OUT_DIM 4096
#define CAUSES_DIM 256
#define POOLED_DIM 1024

typedef __attribute__((ext_vector_type(8))) short short8;
typedef __attribute__((ext_vector_type(4))) float f32x4;

static constexpr float LR = 0.001f;
static constexpr float GAMMA = 0.1f;

enum { EP_R = 0, EP_OUT, EP_UUP };

__device__ __forceinline__ float softthr(float v, float t) {
    return fmaxf(v - t, 0.0f) + fminf(v + t, 0.0f);
}
__device__ __forceinline__ unsigned short f2bf(float f) {
    unsigned int u = __builtin_bit_cast(unsigned int, f);
    u = (u + 0x7fffu + ((u >> 16) & 1u)) >> 16;
    return (unsigned short)u;
}
__device__ __forceinline__ float bf2f(unsigned short h) {
    return __builtin_bit_cast(float, (unsigned int)h << 16);
}
__device__ __forceinline__ void gload_lds16(const unsigned short* g, unsigned short* l) {
    __builtin_amdgcn_global_load_lds(
        (const __attribute__((address_space(1))) void*)g,
        (__attribute__((address_space(3))) void*)l, 16, 0, 0);
}

// stage ROWS x 64 bf16 tile; linear LDS dest, inverse-swizzled global source.
template<int ROWS, int K>
__device__ __forceinline__ void stage_tile(const unsigned short* __restrict__ g,
                                           unsigned short* l, int row0, int k0, int t)
{
#pragma unroll
    for (int j = 0; j < ROWS / 32; j++) {
        const int idx = j * 256 + t;
        const int row = idx >> 3;
        const int sl  = (idx & 7) ^ (row & 7);
        gload_lds16(g + (size_t)(row0 + row) * K + k0 + sl * 8,
                    l + (size_t)(idx & ~63) * 8);
    }
}

// ---------------------------------------------------------------------------
// 3-buffer counted-vmcnt pipelined K-loop (T3+T4; r6-verified). Per stage each
// wave issues L=(BM+BN)/32 global_load_lds; steady state keeps 2 stages (2L)
// in flight; tail peels vmcnt(L) then vmcnt(0).
// ---------------------------------------------------------------------------
template<int BM, int BN, int K>
__device__ __forceinline__ void kloop3(unsigned short* lds,
    const unsigned short* __restrict__ A, const unsigned short* __restrict__ B,
    int m0, int n0, f32x4 (&acc)[BM / 32][BN / 32])
{
    constexpr int FM = BM / 32, FN = BN / 32;
    constexpr int NK = K / 64, ST = (BM + BN) * 64, L = (BM + BN) / 32;
    static_assert(NK >= 3, "pipeline needs >=3 K-tiles");
    const int t = threadIdx.x;
    const int lane = t & 63, wid = t >> 6;
    const int l15 = lane & 15, l7 = lane & 7, g = lane >> 4;
    const int wm0 = (wid >> 1) * (BM / 2), wn0 = (wid & 1) * (BN / 2);

    auto stage = [&](int s, int b) {
        stage_tile<BM, K>(A, lds + b * ST, m0, s * 64, t);
        stage_tile<BN, K>(B, lds + b * ST + BM * 64, n0, s * 64, t);
    };
    auto comp = [&](int b) {
        const unsigned short* As = lds + b * ST;
        const unsigned short* Bs = lds + b * ST + BM * 64;
#pragma unroll
        for (int ks = 0; ks < 2; ks++) {
            const int so = (((ks * 4) + g) ^ l7) * 8;
            short8 af[FM], bfv[FN];
#pragma unroll
            for (int fi = 0; fi < FM; fi++)
                af[fi] = *(const short8*)&As[(wm0 + fi * 16 + l15) * 64 + so];
#pragma unroll
            for (int fj = 0; fj < FN; fj++)
                bfv[fj] = *(const short8*)&Bs[(wn0 + fj * 16 + l15) * 64 + so];
#pragma unroll
            for (int fi = 0; fi < FM; fi++)
#pragma unroll
                for (int fj = 0; fj < FN; fj++)
                    acc[fi][fj] = __builtin_amdgcn_mfma_f32_16x16x32_bf16(
                        af[fi], bfv[fj], acc[fi][fj], 0, 0, 0);
        }
    };

    stage(0, 0); stage(1, 1); stage(2, 2);
    int b = 0;
#pragma unroll 1
    for (int i = 0; i < NK - 2; ++i) {
        asm volatile("s_waitcnt vmcnt(%0)" :: "n"(2 * L) : "memory");
        __builtin_amdgcn_s_barrier();      // stage(i) landed for all waves
        comp(b);
        __builtin_amdgcn_s_barrier();      // all waves done reading buf b
        if (i + 3 < NK) stage(i + 3, b);
        b = (b == 2) ? 0 : b + 1;
    }
    asm volatile("s_waitcnt vmcnt(%0)" :: "n"(L) : "memory");
    __builtin_amdgcn_s_barrier();
    comp(b);
    b = (b == 2) ? 0 : b + 1;
    asm volatile("s_waitcnt vmcnt(0)" ::: "memory");
    __builtin_amdgcn_s_barrier();
    comp(b);
}

// ---------------------------------------------------------------------------
// 2-buffer counted-vmcnt kloop (used by xupc; unchanged from r7/r8)
// ---------------------------------------------------------------------------
template<int BM, int BN, int K>
__device__ __forceinline__ void kloop2(unsigned short* lds,
    const unsigned short* __restrict__ A, const unsigned short* __restrict__ B,
    int m0, int n0, f32x4 (&acc)[BM / 32][BN / 32])
{
    constexpr int FM = BM / 32, FN = BN / 32;
    constexpr int NK = K / 64, ST = (BM + BN) * 64, L = (BM + BN) / 32;
    static_assert(NK >= 2, "pipeline needs >=2 K-tiles");
    const int t = threadIdx.x;
    const int lane = t & 63, wid = t >> 6;
    const int l15 = lane & 15, l7 = lane & 7, g = lane >> 4;
    const int wm0 = (wid >> 1) * (BM / 2), wn0 = (wid & 1) * (BN / 2);

    auto stage = [&](int s, int b) {
        stage_tile<BM, K>(A, lds + b * ST, m0, s * 64, t);
        stage_tile<BN, K>(B, lds + b * ST + BM * 64, n0, s * 64, t);
    };
    auto comp = [&](int b) {
        const unsigned short* As = lds + b * ST;
        const unsigned short* Bs = lds + b * ST + BM * 64;
#pragma unroll
        for (int ks = 0; ks < 2; ks++) {
            const int so = (((ks * 4) + g) ^ l7) * 8;
            short8 af[FM], bfv[FN];
#pragma unroll
            for (int fi = 0; fi < FM; fi++)
                af[fi] = *(const short8*)&As[(wm0 + fi * 16 + l15) * 64 + so];
#pragma unroll
            for (int fj = 0; fj < FN; fj++)
                bfv[fj] = *(const short8*)&Bs[(wn0 + fj * 16 + l15) * 64 + so];
#pragma unroll
            for (int fi = 0; fi < FM; fi++)
#pragma unroll
                for (int fj = 0; fj < FN; fj++)
                    acc[fi][fj] = __builtin_amdgcn_mfma_f32_16x16x32_bf16(
                        af[fi], bfv[fj], acc[fi][fj], 0, 0, 0);
        }
    };

    stage(0, 0); stage(1, 1);
    int b = 0;
#pragma unroll 1
    for (int i = 0; i < NK - 1; ++i) {
        asm volatile("s_waitcnt vmcnt(%0)" :: "n"(L) : "memory");
        __builtin_amdgcn_s_barrier();
        comp(b);
        __builtin_amdgcn_s_barrier();
        if (i + 2 < NK) stage(i + 2, b);
        b ^= 1;
    }
    asm volatile("s_waitcnt vmcnt(0)" ::: "memory");
    __builtin_amdgcn_s_barrier();
    comp(b);
}

// ---------------------------------------------------------------------------
// generic GEMM core (EP_R / EP_OUT / EP_UUP); caller provides m0,n0; kloop3
// ---------------------------------------------------------------------------
template<int BM, int BN, int N, int K, int EP>
__device__ void gemm_core(unsigned short* lds, int m0, int n0,
                          const unsigned short* __restrict__ A,
                          const unsigned short* __restrict__ B,
                          const float* __restrict__ auxf,
                          void* __restrict__ out0, void* __restrict__ out1)
{
    constexpr int FM = BM / 32, FN = BN / 32;
    const int t = threadIdx.x, lane = t & 63, wid = t >> 6;
    const int l15 = lane & 15, g = lane >> 4;
    const int wm0 = (wid >> 1) * (BM / 2), wn0 = (wid & 1) * (BN / 2);

    f32x4 acc[FM][FN];
#pragma unroll
    for (int fi = 0; fi < FM; fi++)
#pragma unroll
        for (int fj = 0; fj < FN; fj++) acc[fi][fj] = (f32x4){0.f, 0.f, 0.f, 0.f};

    kloop3<BM, BN, K>(lds, A, B, m0, n0, acc);

#pragma unroll
    for (int fi = 0; fi < FM; fi++) {
#pragma unroll
        for (int fj = 0; fj < FN; fj++) {
#pragma unroll
            for (int r = 0; r < 4; r++) {
                const int row = m0 + wm0 + fi * 16 + g * 4 + r;
                const int col = n0 + wn0 + fj * 16 + l15;
                const float v = acc[fi][fj][r];
                if (EP == EP_R) {
                    ((unsigned short*)out0)[(size_t)row * N + col] =
                        f2bf(v - auxf[(size_t)row * N + col]);
                } else if (EP == EP_OUT) {
                    ((float*)out0)[(size_t)row * N + col] = v;
                } else { // EP_UUP
                    float* up = (float*)out0;
                    const size_t idx = (size_t)row * CAUSES_DIM + col;
                    const float uv = softthr(up[idx] - LR * v, LR * GAMMA * 0.1f);
                    up[idx] = uv;
                    ((unsigned short*)out1)[idx] = f2bf(uv);
                }
            }
        }
    }
}

// ---------------------------------------------------------------------------
// XUPC: x-update GEMM (R@W^T, 128x128) + causes mini-GEMM (u@V) + fused pool.
// LDS: 2x32KB pipeline buffers + 16KB czdc = 80KB -> 2 blocks/CU.
// UNCHANGED from r7/r8 (it dropped below the h floor there).
// ---------------------------------------------------------------------------
template<bool FIRST, bool POOLF>
__global__ __launch_bounds__(256)
void xupc_kernel(const unsigned short* __restrict__ Rbf,
                 const unsigned short* __restrict__ Wbf,
                 const unsigned short* __restrict__ ubf,
                 const unsigned short* __restrict__ VTbf,
                 unsigned short* __restrict__ xbf,
                 unsigned short* __restrict__ gbf)
{
    constexpr int BM = 128, BN = 128;
    __shared__ unsigned short lds[2 * (BM + BN) * 64 + 8192];  // 80 KB
    unsigned* czdc = (unsigned*)(lds + 2 * (BM + BN) * 64);    // [128][32] cz|dc
    unsigned short* xs = lds;                                  // pool tile 128x130

    const int t = threadIdx.x, lane = t & 63, wid = t >> 6;
    const int l15 = lane & 15, g = lane >> 4;
    const int xcd = blockIdx.x & 7, l = blockIdx.x >> 3;       // l in [0,128)
    const int g2 = l >> 5, r2 = l & 31;
    const int bm = g2 * 8 + (r2 >> 2), bn = xcd * 4 + (r2 & 3);
    const int m0 = bm * BM, n0 = bn * BN;
    const int wm0 = (wid >> 1) * 64, wn0 = (wid & 1) * 64;

    f32x4 acc[4][4];
#pragma unroll
    for (int fi = 0; fi < 4; fi++)
#pragma unroll
        for (int fj = 0; fj < 4; fj++) acc[fi][fj] = (f32x4){0.f, 0.f, 0.f, 0.f};
    kloop2<128, 128, IN_DIM>(lds, Rbf, Wbf, m0, n0, acc);
    __syncthreads();

    // causes mini-GEMM: z[128x32] = u[m0:,:] @ VT rows [bn*32, bn*32+32)
    f32x4 zacc[4][1];
#pragma unroll
    for (int fi = 0; fi < 4; fi++) zacc[fi][0] = (f32x4){0.f, 0.f, 0.f, 0.f};
    kloop2<128, 32, CAUSES_DIM>(lds, ubf, VTbf, m0, bn * 32, zacc);

    {   // z epilogue -> czdc (cz low16 | dc high16), bf16-rounded
        const int zc = (wid & 1) * 16 + l15;
#pragma unroll
        for (int fi = 0; fi < 4; fi++) {
#pragma unroll
            for (int r = 0; r < 4; r++) {
                const int zr = (wid >> 1) * 64 + fi * 16 + g * 4 + r;
                const float e = expf(-zacc[fi][0][r]);
                czdc[zr * 32 + zc] =
                    (unsigned)f2bf(0.5f + 0.5f * e) | ((unsigned)f2bf(-0.5f * e) << 16);
            }
        }
    }
    __syncthreads();

    // x-update epilogue
#pragma unroll
    for (int fi = 0; fi < 4; fi++) {
#pragma unroll
        for (int fj = 0; fj < 4; fj++) {
#pragma unroll
            for (int r = 0; r < 4; r++) {
                const int rloc = wm0 + fi * 16 + g * 4 + r;
                const int cloc = wn0 + fj * 16 + l15;
                const int pl = (cloc & 63) >> 1;
                const float cz = bf2f((unsigned short)(czdc[rloc * 32 + pl] & 0xffffu));
                const size_t idx = (size_t)(m0 + rloc) * OUT_DIM + n0 + cloc;
                const float xold = FIRST ? 0.0f : bf2f(xbf[idx]);
                const float xv = softthr(xold - 2.0f * LR * acc[fi][fj][r],
                                         LR * GAMMA * cz);
                const unsigned short xq = f2bf(xv);
                xbf[idx] = xq;
                if (POOLF) xs[rloc * 130 + cloc] = xq;
            }
        }
    }

    // fused maxpool2x2 + gin
    if (POOLF) {
        __syncthreads();
        const int p = t & 31;              // local pooled col
        const int rbase = (t >> 5) * 16;   // 8 groups x 16 rows
#pragma unroll
        for (int i = 0; i < 16; i++) {
            const int prow = rbase + i;
            const unsigned short* xr = &xs[prow * 130 + 2 * p];
            const float mx = fmaxf(fmaxf(bf2f(xr[0]), bf2f(xr[1])),
                                   fmaxf(bf2f(xr[64]), bf2f(xr[65])));
            const float dcv = bf2f((unsigned short)(czdc[prow * 32 + p] >> 16));
            gbf[(size_t)(m0 + prow) * POOLED_DIM + bn * 32 + p] = f2bf(dcv * mx * GAMMA);
        }
    }
}

// ---------------------------------------------------------------------------
// H: horizontal fusion of UUP_t (256 blocks) and R_{t+1} (256 blocks).
// R decode: XCD m-ownership — xcd=bid&7 owns m-blocks [4*xcd,4*xcd+4),
// n-fastest within. A-panels (1MB) are read by exactly one XCD and reused 8x
// through its L2; concurrent per-XCD footprint ~4MB A + 4MB WT.
// ---------------------------------------------------------------------------
__global__ __launch_bounds__(256)
void h_uup_r_kernel(const unsigned short* __restrict__ gbf,
                    const unsigned short* __restrict__ Vbf,
                    float* __restrict__ u, unsigned short* __restrict__ ubf,
                    const unsigned short* __restrict__ xbf,
                    const unsigned short* __restrict__ WTbf,
                    const float* __restrict__ inputs,
                    unsigned short* __restrict__ Rbf)
{
    __shared__ unsigned short lds[3 * (128 + 64) * 64];   // 72 KB
    if (blockIdx.x < 256) {
        const int bid = blockIdx.x;
        const int xcd = bid & 7, l = bid >> 3;            // l in [0,32)
        const int bm = xcd * 4 + (l >> 3);                // m-ownership per XCD
        const int bn = l & 7;                             // n-fastest
        gemm_core<128, 64, IN_DIM, OUT_DIM, EP_R>(
            lds, bm * 128, bn * 64, xbf, WTbf, inputs, Rbf, nullptr);
    } else {
        const int bid = blockIdx.x - 256;
        gemm_core<64, 64, CAUSES_DIM, POOLED_DIM, EP_UUP>(
            lds, (bid >> 2) * 64, (bid & 3) * 64, gbf, Vbf, nullptr, u, ubf);
    }
}

__global__ __launch_bounds__(256)
void out_kernel(const unsigned short* __restrict__ xbf,
                const unsigned short* __restrict__ WTbf,
                float* __restrict__ out)
{
    __shared__ unsigned short lds[3 * (128 + 64) * 64];
    const int bid = blockIdx.x;
    const int xcd = bid & 7, l = bid >> 3;
    const int bm = xcd * 4 + (l >> 3);
    const int bn = l & 7;
    gemm_core<128, 64, IN_DIM, OUT_DIM, EP_OUT>(
        lds, bm * 128, bn * 64, xbf, WTbf, nullptr, out, nullptr);
}

// ---------------------------------------------------------------------------
// setup kernels
// ---------------------------------------------------------------------------
// cast + transpose in one pass: direct[r][c]=bf(in[r][c]); transp[c][r]=same
__global__ __launch_bounds__(256)
void prep_k(const float* __restrict__ in, unsigned short* __restrict__ direct,
            unsigned short* __restrict__ transp, int R, int C)
{
    __shared__ float tile[32][33];
    const int bx = blockIdx.x * 32, by = blockIdx.y * 32;
    const int tx = threadIdx.x % 32, ty = threadIdx.x / 32;
#pragma unroll
    for (int i = 0; i < 32; i += 8) {
        const float v = in[(size_t)(by + ty + i) * C + bx + tx];
        tile[ty + i][tx] = v;
        direct[(size_t)(by + ty + i) * C + bx + tx] = f2bf(v);
    }
    __syncthreads();
#pragma unroll
    for (int i = 0; i < 32; i += 8)
        transp[(size_t)(bx + ty + i) * R + by + tx] = f2bf(tile[tx][ty + i]);
}

__global__ void negcast_k(const float* __restrict__ in, unsigned short* __restrict__ out,
                          int n4)
{
    const int i = blockIdx.x * 256 + threadIdx.x;
    if (i >= n4) return;
    float4 v = ((const float4*)in)[i];
    union { unsigned short s[4]; unsigned long long u; } p;
    p.s[0] = f2bf(-v.x); p.s[1] = f2bf(-v.y); p.s[2] = f2bf(-v.z); p.s[3] = f2bf(-v.w);
    ((unsigned long long*)out)[i] = p.u;
}

__global__ void fill_u_k(float* __restrict__ u, unsigned short* __restrict__ ubf, int n) {
    const int i = blockIdx.x * 256 + threadIdx.x;
    if (i >= n) return;
    u[i] = 0.1f;
    ubf[i] = f2bf(0.1f);
}

extern "C" void kernel_launch(void* const* d_in, const int* in_sizes, int n_in,
                              void* d_out, int out_size, void* d_ws, size_t ws_size,
                              hipStream_t stream)
{
    const float* inputs = (const float*)d_in[0];   // [4096, 512]
    const float* W      = (const float*)d_in[1];   // [4096, 512]
    const float* V      = (const float*)d_in[2];   // [256, 1024]
    float* out = (float*)d_out;                    // [4096, 512]

    // workspace (~59 MB)
    char* w = (char*)d_ws;
    unsigned short* xbf  = (unsigned short*)w; w += (size_t)NB * OUT_DIM * 2;
    unsigned short* Rbf  = (unsigned short*)w; w += (size_t)NB * IN_DIM * 2;
    unsigned short* gbf  = (unsigned short*)w; w += (size_t)NB * POOLED_DIM * 2;
    float*          u    = (float*)w;          w += (size_t)NB * CAUSES_DIM * 4;
    unsigned short* ubf  = (unsigned short*)w; w += (size_t)NB * CAUSES_DIM * 2;
    unsigned short* Wbf  = (unsigned short*)w; w += (size_t)OUT_DIM * IN_DIM * 2;
    unsigned short* WTbf = (unsigned short*)w; w += (size_t)OUT_DIM * IN_DIM * 2;
    unsigned short* Vbf  = (unsigned short*)w; w += (size_t)CAUSES_DIM * POOLED_DIM * 2;
    unsigned short* VTbf = (unsigned short*)w;

    // ---- setup (4 launches) ----
    prep_k<<<dim3(IN_DIM / 32, OUT_DIM / 32), 256, 0, stream>>>(W, Wbf, WTbf, OUT_DIM, IN_DIM);
    prep_k<<<dim3(POOLED_DIM / 32, CAUSES_DIM / 32), 256, 0, stream>>>(V, Vbf, VTbf, CAUSES_DIM, POOLED_DIM);
    fill_u_k<<<NB * CAUSES_DIM / 256, 256, 0, stream>>>(u, ubf, NB * CAUSES_DIM);
    negcast_k<<<NB * IN_DIM / 4 / 256, 256, 0, stream>>>(inputs, Rbf, NB * IN_DIM / 4); // R0=-inputs

    // ---- 10-step scan ----
    xupc_kernel<true, true><<<1024, 256, 0, stream>>>(Rbf, Wbf, ubf, VTbf, xbf, gbf); // t=0, x=0
    h_uup_r_kernel<<<512, 256, 0, stream>>>(gbf, Vbf, u, ubf, xbf, WTbf, inputs, Rbf);
    for (int t = 1; t < 8; t++) {
        xupc_kernel<false, true><<<1024, 256, 0, stream>>>(Rbf, Wbf, ubf, VTbf, xbf, gbf);
        h_uup_r_kernel<<<512, 256, 0, stream>>>(gbf, Vbf, u, ubf, xbf, WTbf, inputs, Rbf);
    }
    xupc_kernel<false, false><<<1024, 256, 0, stream>>>(Rbf, Wbf, ubf, VTbf, xbf, gbf); // t=8
    out_kernel<<<256, 256, 0, stream>>>(xbf, WTbf, out);                                 // rec = x9@W
}

// Round 10
// 682.376 us; speedup vs baseline: 1.2442x; 1.0802x over previous
//
#include <hip/hip_runtime.h>
#include <math.h>

// Sparse2L round 10: T14-style reg-fragment K-loops — per iteration:
// {counted vmcnt -> barrier -> ds_read ALL frags to regs -> lgkmcnt(0) ->
//  barrier -> stage next tile into freed buffer -> setprio+MFMA cluster}.
// Geometry/decodes identical to round 9 (XCD m-ownership for h/out, 2-level
// decode for xupc). Math order unchanged -> bit-identical output.
//  per step: R = x@W - inputs; z = u@V (mini-GEMM in XUPC);
//            x = softthr(x - 2lr*(R@W^T), lr*gamma*up((1+e^-z)/2));  [x bf16]
//            gin = (-e^-z/2) * maxpool2x2(x) * gamma  (fused pool phase);
//            u = softthr(u - lr*(gin@V^T), lr*gamma/10)   [in H kernel]
//  output = x9 @ W

#define NB 4096
#define IN_DIM 512
#define OUT_DIM 4096
#define CAUSES_DIM 256
#define POOLED_DIM 1024

typedef __attribute__((ext_vector_type(8))) short short8;
typedef __attribute__((ext_vector_type(4))) float f32x4;

static constexpr float LR = 0.001f;
static constexpr float GAMMA = 0.1f;

enum { EP_R = 0, EP_OUT, EP_UUP };

__device__ __forceinline__ float softthr(float v, float t) {
    return fmaxf(v - t, 0.0f) + fminf(v + t, 0.0f);
}
__device__ __forceinline__ unsigned short f2bf(float f) {
    unsigned int u = __builtin_bit_cast(unsigned int, f);
    u = (u + 0x7fffu + ((u >> 16) & 1u)) >> 16;
    return (unsigned short)u;
}
__device__ __forceinline__ float bf2f(unsigned short h) {
    return __builtin_bit_cast(float, (unsigned int)h << 16);
}
__device__ __forceinline__ void gload_lds16(const unsigned short* g, unsigned short* l) {
    __builtin_amdgcn_global_load_lds(
        (const __attribute__((address_space(1))) void*)g,
        (__attribute__((address_space(3))) void*)l, 16, 0, 0);
}

// stage ROWS x 64 bf16 tile; linear LDS dest, inverse-swizzled global source.
template<int ROWS, int K>
__device__ __forceinline__ void stage_tile(const unsigned short* __restrict__ g,
                                           unsigned short* l, int row0, int k0, int t)
{
#pragma unroll
    for (int j = 0; j < ROWS / 32; j++) {
        const int idx = j * 256 + t;
        const int row = idx >> 3;
        const int sl  = (idx & 7) ^ (row & 7);
        gload_lds16(g + (size_t)(row0 + row) * K + k0 + sl * 8,
                    l + (size_t)(idx & ~63) * 8);
    }
}

// ---------------------------------------------------------------------------
// 3-buffer counted-vmcnt pipelined K-loop, reg-fragment cluster form.
// Steady state keeps 2 stages (2L) in flight; frags for the whole K-step are
// pulled to registers BEFORE the freed buffer is overwritten, so the next
// stage is issued ahead of the MFMA cluster (T14) and MFMA runs as a pure-reg
// cluster under setprio (T5).
// ---------------------------------------------------------------------------
template<int BM, int BN, int K>
__device__ __forceinline__ void kloop3(unsigned short* lds,
    const unsigned short* __restrict__ A, const unsigned short* __restrict__ B,
    int m0, int n0, f32x4 (&acc)[BM / 32][BN / 32])
{
    constexpr int FM = BM / 32, FN = BN / 32;
    constexpr int NK = K / 64, ST = (BM + BN) * 64, L = (BM + BN) / 32;
    static_assert(NK >= 3, "pipeline needs >=3 K-tiles");
    const int t = threadIdx.x;
    const int lane = t & 63, wid = t >> 6;
    const int l15 = lane & 15, l7 = lane & 7, g = lane >> 4;
    const int wm0 = (wid >> 1) * (BM / 2), wn0 = (wid & 1) * (BN / 2);

    auto stage = [&](int s, int b) {
        stage_tile<BM, K>(A, lds + b * ST, m0, s * 64, t);
        stage_tile<BN, K>(B, lds + b * ST + BM * 64, n0, s * 64, t);
    };

    short8 af[2][FM], bfv[2][FN];
    auto readfrags = [&](int b) {
        const unsigned short* As = lds + b * ST;
        const unsigned short* Bs = lds + b * ST + BM * 64;
#pragma unroll
        for (int ks = 0; ks < 2; ks++) {
            const int so = (((ks * 4) + g) ^ l7) * 8;
#pragma unroll
            for (int fi = 0; fi < FM; fi++)
                af[ks][fi] = *(const short8*)&As[(wm0 + fi * 16 + l15) * 64 + so];
#pragma unroll
            for (int fj = 0; fj < FN; fj++)
                bfv[ks][fj] = *(const short8*)&Bs[(wn0 + fj * 16 + l15) * 64 + so];
        }
    };
    auto mfma_all = [&]() {
        __builtin_amdgcn_s_setprio(1);
#pragma unroll
        for (int ks = 0; ks < 2; ks++)
#pragma unroll
            for (int fi = 0; fi < FM; fi++)
#pragma unroll
                for (int fj = 0; fj < FN; fj++)
                    acc[fi][fj] = __builtin_amdgcn_mfma_f32_16x16x32_bf16(
                        af[ks][fi], bfv[ks][fj], acc[fi][fj], 0, 0, 0);
        __builtin_amdgcn_s_setprio(0);
    };

    stage(0, 0); stage(1, 1); stage(2, 2);
    int b = 0;
#pragma unroll 1
    for (int i = 0; i < NK; ++i) {
        if (i < NK - 2)
            asm volatile("s_waitcnt vmcnt(%0)" :: "n"(2 * L) : "memory");
        else if (i == NK - 2)
            asm volatile("s_waitcnt vmcnt(%0)" :: "n"(L) : "memory");
        else
            asm volatile("s_waitcnt vmcnt(0)" ::: "memory");
        __builtin_amdgcn_s_barrier();              // stage(i) visible to all
        readfrags(b);                              // LDS -> regs, whole K-step
        asm volatile("s_waitcnt lgkmcnt(0)" ::: "memory");
        __builtin_amdgcn_sched_barrier(0);         // rule-18 fence
        __builtin_amdgcn_s_barrier();              // all waves done reading b
        if (i + 3 < NK) stage(i + 3, b);           // overwrite freed buffer
        mfma_all();                                // pure-reg MFMA cluster
        b = (b == 2) ? 0 : b + 1;
    }
}

// ---------------------------------------------------------------------------
// 2-buffer variant (xupc main + mini GEMM), same reg-fragment cluster form.
// ---------------------------------------------------------------------------
template<int BM, int BN, int K>
__device__ __forceinline__ void kloop2(unsigned short* lds,
    const unsigned short* __restrict__ A, const unsigned short* __restrict__ B,
    int m0, int n0, f32x4 (&acc)[BM / 32][BN / 32])
{
    constexpr int FM = BM / 32, FN = BN / 32;
    constexpr int NK = K / 64, ST = (BM + BN) * 64, L = (BM + BN) / 32;
    static_assert(NK >= 2, "pipeline needs >=2 K-tiles");
    const int t = threadIdx.x;
    const int lane = t & 63, wid = t >> 6;
    const int l15 = lane & 15, l7 = lane & 7, g = lane >> 4;
    const int wm0 = (wid >> 1) * (BM / 2), wn0 = (wid & 1) * (BN / 2);

    auto stage = [&](int s, int b) {
        stage_tile<BM, K>(A, lds + b * ST, m0, s * 64, t);
        stage_tile<BN, K>(B, lds + b * ST + BM * 64, n0, s * 64, t);
    };

    short8 af[2][FM], bfv[2][FN];
    auto readfrags = [&](int b) {
        const unsigned short* As = lds + b * ST;
        const unsigned short* Bs = lds + b * ST + BM * 64;
#pragma unroll
        for (int ks = 0; ks < 2; ks++) {
            const int so = (((ks * 4) + g) ^ l7) * 8;
#pragma unroll
            for (int fi = 0; fi < FM; fi++)
                af[ks][fi] = *(const short8*)&As[(wm0 + fi * 16 + l15) * 64 + so];
#pragma unroll
            for (int fj = 0; fj < FN; fj++)
                bfv[ks][fj] = *(const short8*)&Bs[(wn0 + fj * 16 + l15) * 64 + so];
        }
    };
    auto mfma_all = [&]() {
        __builtin_amdgcn_s_setprio(1);
#pragma unroll
        for (int ks = 0; ks < 2; ks++)
#pragma unroll
            for (int fi = 0; fi < FM; fi++)
#pragma unroll
                for (int fj = 0; fj < FN; fj++)
                    acc[fi][fj] = __builtin_amdgcn_mfma_f32_16x16x32_bf16(
                        af[ks][fi], bfv[ks][fj], acc[fi][fj], 0, 0, 0);
        __builtin_amdgcn_s_setprio(0);
    };

    stage(0, 0); stage(1, 1);
    int b = 0;
#pragma unroll 1
    for (int i = 0; i < NK; ++i) {
        if (i < NK - 1)
            asm volatile("s_waitcnt vmcnt(%0)" :: "n"(L) : "memory");
        else
            asm volatile("s_waitcnt vmcnt(0)" ::: "memory");
        __builtin_amdgcn_s_barrier();
        readfrags(b);
        asm volatile("s_waitcnt lgkmcnt(0)" ::: "memory");
        __builtin_amdgcn_sched_barrier(0);
        __builtin_amdgcn_s_barrier();
        if (i + 2 < NK) stage(i + 2, b);
        mfma_all();
        b ^= 1;
    }
}

// ---------------------------------------------------------------------------
// generic GEMM core (EP_R / EP_OUT / EP_UUP); caller provides m0,n0; kloop3
// ---------------------------------------------------------------------------
template<int BM, int BN, int N, int K, int EP>
__device__ void gemm_core(unsigned short* lds, int m0, int n0,
                          const unsigned short* __restrict__ A,
                          const unsigned short* __restrict__ B,
                          const float* __restrict__ auxf,
                          void* __restrict__ out0, void* __restrict__ out1)
{
    constexpr int FM = BM / 32, FN = BN / 32;
    const int t = threadIdx.x, lane = t & 63, wid = t >> 6;
    const int l15 = lane & 15, g = lane >> 4;
    const int wm0 = (wid >> 1) * (BM / 2), wn0 = (wid & 1) * (BN / 2);

    f32x4 acc[FM][FN];
#pragma unroll
    for (int fi = 0; fi < FM; fi++)
#pragma unroll
        for (int fj = 0; fj < FN; fj++) acc[fi][fj] = (f32x4){0.f, 0.f, 0.f, 0.f};

    kloop3<BM, BN, K>(lds, A, B, m0, n0, acc);

#pragma unroll
    for (int fi = 0; fi < FM; fi++) {
#pragma unroll
        for (int fj = 0; fj < FN; fj++) {
#pragma unroll
            for (int r = 0; r < 4; r++) {
                const int row = m0 + wm0 + fi * 16 + g * 4 + r;
                const int col = n0 + wn0 + fj * 16 + l15;
                const float v = acc[fi][fj][r];
                if (EP == EP_R) {
                    ((unsigned short*)out0)[(size_t)row * N + col] =
                        f2bf(v - auxf[(size_t)row * N + col]);
                } else if (EP == EP_OUT) {
                    ((float*)out0)[(size_t)row * N + col] = v;
                } else { // EP_UUP
                    float* up = (float*)out0;
                    const size_t idx = (size_t)row * CAUSES_DIM + col;
                    const float uv = softthr(up[idx] - LR * v, LR * GAMMA * 0.1f);
                    up[idx] = uv;
                    ((unsigned short*)out1)[idx] = f2bf(uv);
                }
            }
        }
    }
}

// ---------------------------------------------------------------------------
// XUPC: x-update GEMM (R@W^T, 128x128) + causes mini-GEMM (u@V) + fused pool.
// LDS: 2x32KB pipeline buffers + 16KB czdc = 80KB -> 2 blocks/CU.
// Decode unchanged from r7-r9 (verified: dropped below the h floor).
// ---------------------------------------------------------------------------
template<bool FIRST, bool POOLF>
__global__ __launch_bounds__(256)
void xupc_kernel(const unsigned short* __restrict__ Rbf,
                 const unsigned short* __restrict__ Wbf,
                 const unsigned short* __restrict__ ubf,
                 const unsigned short* __restrict__ VTbf,
                 unsigned short* __restrict__ xbf,
                 unsigned short* __restrict__ gbf)
{
    constexpr int BM = 128, BN = 128;
    __shared__ unsigned short lds[2 * (BM + BN) * 64 + 8192];  // 80 KB
    unsigned* czdc = (unsigned*)(lds + 2 * (BM + BN) * 64);    // [128][32] cz|dc
    unsigned short* xs = lds;                                  // pool tile 128x130

    const int t = threadIdx.x, lane = t & 63, wid = t >> 6;
    const int l15 = lane & 15, g = lane >> 4;
    const int xcd = blockIdx.x & 7, l = blockIdx.x >> 3;       // l in [0,128)
    const int g2 = l >> 5, r2 = l & 31;
    const int bm = g2 * 8 + (r2 >> 2), bn = xcd * 4 + (r2 & 3);
    const int m0 = bm * BM, n0 = bn * BN;
    const int wm0 = (wid >> 1) * 64, wn0 = (wid & 1) * 64;

    f32x4 acc[4][4];
#pragma unroll
    for (int fi = 0; fi < 4; fi++)
#pragma unroll
        for (int fj = 0; fj < 4; fj++) acc[fi][fj] = (f32x4){0.f, 0.f, 0.f, 0.f};
    kloop2<128, 128, IN_DIM>(lds, Rbf, Wbf, m0, n0, acc);
    __syncthreads();

    // causes mini-GEMM: z[128x32] = u[m0:,:] @ VT rows [bn*32, bn*32+32)
    f32x4 zacc[4][1];
#pragma unroll
    for (int fi = 0; fi < 4; fi++) zacc[fi][0] = (f32x4){0.f, 0.f, 0.f, 0.f};
    kloop2<128, 32, CAUSES_DIM>(lds, ubf, VTbf, m0, bn * 32, zacc);

    {   // z epilogue -> czdc (cz low16 | dc high16), bf16-rounded
        const int zc = (wid & 1) * 16 + l15;
#pragma unroll
        for (int fi = 0; fi < 4; fi++) {
#pragma unroll
            for (int r = 0; r < 4; r++) {
                const int zr = (wid >> 1) * 64 + fi * 16 + g * 4 + r;
                const float e = expf(-zacc[fi][0][r]);
                czdc[zr * 32 + zc] =
                    (unsigned)f2bf(0.5f + 0.5f * e) | ((unsigned)f2bf(-0.5f * e) << 16);
            }
        }
    }
    __syncthreads();

    // x-update epilogue
#pragma unroll
    for (int fi = 0; fi < 4; fi++) {
#pragma unroll
        for (int fj = 0; fj < 4; fj++) {
#pragma unroll
            for (int r = 0; r < 4; r++) {
                const int rloc = wm0 + fi * 16 + g * 4 + r;
                const int cloc = wn0 + fj * 16 + l15;
                const int pl = (cloc & 63) >> 1;
                const float cz = bf2f((unsigned short)(czdc[rloc * 32 + pl] & 0xffffu));
                const size_t idx = (size_t)(m0 + rloc) * OUT_DIM + n0 + cloc;
                const float xold = FIRST ? 0.0f : bf2f(xbf[idx]);
                const float xv = softthr(xold - 2.0f * LR * acc[fi][fj][r],
                                         LR * GAMMA * cz);
                const unsigned short xq = f2bf(xv);
                xbf[idx] = xq;
                if (POOLF) xs[rloc * 130 + cloc] = xq;
            }
        }
    }

    // fused maxpool2x2 + gin
    if (POOLF) {
        __syncthreads();
        const int p = t & 31;              // local pooled col
        const int rbase = (t >> 5) * 16;   // 8 groups x 16 rows
#pragma unroll
        for (int i = 0; i < 16; i++) {
            const int prow = rbase + i;
            const unsigned short* xr = &xs[prow * 130 + 2 * p];
            const float mx = fmaxf(fmaxf(bf2f(xr[0]), bf2f(xr[1])),
                                   fmaxf(bf2f(xr[64]), bf2f(xr[65])));
            const float dcv = bf2f((unsigned short)(czdc[prow * 32 + p] >> 16));
            gbf[(size_t)(m0 + prow) * POOLED_DIM + bn * 32 + p] = f2bf(dcv * mx * GAMMA);
        }
    }
}

// ---------------------------------------------------------------------------
// H: horizontal fusion of UUP_t (256 blocks) and R_{t+1} (256 blocks).
// R decode: XCD m-ownership (xcd=bid&7 owns 4 m-blocks, n-fastest).
// ---------------------------------------------------------------------------
__global__ __launch_bounds__(256)
void h_uup_r_kernel(const unsigned short* __restrict__ gbf,
                    const unsigned short* __restrict__ Vbf,
                    float* __restrict__ u, unsigned short* __restrict__ ubf,
                    const unsigned short* __restrict__ xbf,
                    const unsigned short* __restrict__ WTbf,
                    const float* __restrict__ inputs,
                    unsigned short* __restrict__ Rbf)
{
    __shared__ unsigned short lds[3 * (128 + 64) * 64];   // 72 KB
    if (blockIdx.x < 256) {
        const int bid = blockIdx.x;
        const int xcd = bid & 7, l = bid >> 3;            // l in [0,32)
        const int bm = xcd * 4 + (l >> 3);                // m-ownership per XCD
        const int bn = l & 7;                             // n-fastest
        gemm_core<128, 64, IN_DIM, OUT_DIM, EP_R>(
            lds, bm * 128, bn * 64, xbf, WTbf, inputs, Rbf, nullptr);
    } else {
        const int bid = blockIdx.x - 256;
        gemm_core<64, 64, CAUSES_DIM, POOLED_DIM, EP_UUP>(
            lds, (bid >> 2) * 64, (bid & 3) * 64, gbf, Vbf, nullptr, u, ubf);
    }
}

__global__ __launch_bounds__(256)
void out_kernel(const unsigned short* __restrict__ xbf,
                const unsigned short* __restrict__ WTbf,
                float* __restrict__ out)
{
    __shared__ unsigned short lds[3 * (128 + 64) * 64];
    const int bid = blockIdx.x;
    const int xcd = bid & 7, l = bid >> 3;
    const int bm = xcd * 4 + (l >> 3);
    const int bn = l & 7;
    gemm_core<128, 64, IN_DIM, OUT_DIM, EP_OUT>(
        lds, bm * 128, bn * 64, xbf, WTbf, nullptr, out, nullptr);
}

// ---------------------------------------------------------------------------
// setup kernels
// ---------------------------------------------------------------------------
// cast + transpose in one pass: direct[r][c]=bf(in[r][c]); transp[c][r]=same
__global__ __launch_bounds__(256)
void prep_k(const float* __restrict__ in, unsigned short* __restrict__ direct,
            unsigned short* __restrict__ transp, int R, int C)
{
    __shared__ float tile[32][33];
    const int bx = blockIdx.x * 32, by = blockIdx.y * 32;
    const int tx = threadIdx.x % 32, ty = threadIdx.x / 32;
#pragma unroll
    for (int i = 0; i < 32; i += 8) {
        const float v = in[(size_t)(by + ty + i) * C + bx + tx];
        tile[ty + i][tx] = v;
        direct[(size_t)(by + ty + i) * C + bx + tx] = f2bf(v);
    }
    __syncthreads();
#pragma unroll
    for (int i = 0; i < 32; i += 8)
        transp[(size_t)(bx + ty + i) * R + by + tx] = f2bf(tile[tx][ty + i]);
}

__global__ void negcast_k(const float* __restrict__ in, unsigned short* __restrict__ out,
                          int n4)
{
    const int i = blockIdx.x * 256 + threadIdx.x;
    if (i >= n4) return;
    float4 v = ((const float4*)in)[i];
    union { unsigned short s[4]; unsigned long long u; } p;
    p.s[0] = f2bf(-v.x); p.s[1] = f2bf(-v.y); p.s[2] = f2bf(-v.z); p.s[3] = f2bf(-v.w);
    ((unsigned long long*)out)[i] = p.u;
}

__global__ void fill_u_k(float* __restrict__ u, unsigned short* __restrict__ ubf, int n) {
    const int i = blockIdx.x * 256 + threadIdx.x;
    if (i >= n) return;
    u[i] = 0.1f;
    ubf[i] = f2bf(0.1f);
}

extern "C" void kernel_launch(void* const* d_in, const int* in_sizes, int n_in,
                              void* d_out, int out_size, void* d_ws, size_t ws_size,
                              hipStream_t stream)
{
    const float* inputs = (const float*)d_in[0];   // [4096, 512]
    const float* W      = (const float*)d_in[1];   // [4096, 512]
    const float* V      = (const float*)d_in[2];   // [256, 1024]
    float* out = (float*)d_out;                    // [4096, 512]

    // workspace (~59 MB)
    char* w = (char*)d_ws;
    unsigned short* xbf  = (unsigned short*)w; w += (size_t)NB * OUT_DIM * 2;
    unsigned short* Rbf  = (unsigned short*)w; w += (size_t)NB * IN_DIM * 2;
    unsigned short* gbf  = (unsigned short*)w; w += (size_t)NB * POOLED_DIM * 2;
    float*          u    = (float*)w;          w += (size_t)NB * CAUSES_DIM * 4;
    unsigned short* ubf  = (unsigned short*)w; w += (size_t)NB * CAUSES_DIM * 2;
    unsigned short* Wbf  = (unsigned short*)w; w += (size_t)OUT_DIM * IN_DIM * 2;
    unsigned short* WTbf = (unsigned short*)w; w += (size_t)OUT_DIM * IN_DIM * 2;
    unsigned short* Vbf  = (unsigned short*)w; w += (size_t)CAUSES_DIM * POOLED_DIM * 2;
    unsigned short* VTbf = (unsigned short*)w;

    // ---- setup (4 launches) ----
    prep_k<<<dim3(IN_DIM / 32, OUT_DIM / 32), 256, 0, stream>>>(W, Wbf, WTbf, OUT_DIM, IN_DIM);
    prep_k<<<dim3(POOLED_DIM / 32, CAUSES_DIM / 32), 256, 0, stream>>>(V, Vbf, VTbf, CAUSES_DIM, POOLED_DIM);
    fill_u_k<<<NB * CAUSES_DIM / 256, 256, 0, stream>>>(u, ubf, NB * CAUSES_DIM);
    negcast_k<<<NB * IN_DIM / 4 / 256, 256, 0, stream>>>(inputs, Rbf, NB * IN_DIM / 4); // R0=-inputs

    // ---- 10-step scan ----
    xupc_kernel<true, true><<<1024, 256, 0, stream>>>(Rbf, Wbf, ubf, VTbf, xbf, gbf); // t=0, x=0
    h_uup_r_kernel<<<512, 256, 0, stream>>>(gbf, Vbf, u, ubf, xbf, WTbf, inputs, Rbf);
    for (int t = 1; t < 8; t++) {
        xupc_kernel<false, true><<<1024, 256, 0, stream>>>(Rbf, Wbf, ubf, VTbf, xbf, gbf);
        h_uup_r_kernel<<<512, 256, 0, stream>>>(gbf, Vbf, u, ubf, xbf, WTbf, inputs, Rbf);
    }
    xupc_kernel<false, false><<<1024, 256, 0, stream>>>(Rbf, Wbf, ubf, VTbf, xbf, gbf); // t=8
    out_kernel<<<256, 256, 0, stream>>>(xbf, WTbf, out);                                 // rec = x9@W
}